// Round 1
// 560.617 us; speedup vs baseline: 1.0004x; 1.0004x over previous
//
#include <hip/hip_runtime.h>
#include <math.h>

#define NB 16384   // batch
#define ND 128     // d_model
#define NS 5       // negatives

__global__ __launch_bounds__(256) void ws_negsamp_kernel(
    const float* __restrict__ h,
    const float* __restrict__ emb,
    const int*   __restrict__ tgt,
    const int*   __restrict__ neg,
    float*       __restrict__ out)
{
    const int wave = (blockIdx.x * blockDim.x + threadIdx.x) >> 6;
    const int lane = threadIdx.x & 63;
    const int half = lane >> 5;   // which sample of the pair
    const int hl   = lane & 31;   // lane within 32-lane group
    const int row  = wave;

    // --- issue the h-row load first (independent, 512B per half from L1/L2)
    const float4 hv = *reinterpret_cast<const float4*>(h + (size_t)row * ND + hl * 4);

    // --- ALL 6 sample indices in ONE VMEM instruction:
    //     lane 0 -> tgt[row]; lanes 1..5 -> neg[row*5 + lane-1]; lanes >=6 harmless dup
    const int lm1 = (lane >= 1 && lane <= 5) ? (lane - 1) : 0;
    const int* ip = (lane == 0) ? (tgt + row) : (neg + (size_t)row * NS + lm1);
    const int idxv = *ip;   // sample s lives in lane s (s = 0..5)

    // --- broadcast this half's 3 sample indices (sample s = 2*j + half lives in lane s)
    int myidx[3];
#pragma unroll
    for (int j = 0; j < 3; ++j)
        myidx[j] = __shfl(idxv, 2 * j + half, 64);

    // --- issue all 3 gathers back-to-back BEFORE any reduction arithmetic
    float4 ev[3];
#pragma unroll
    for (int j = 0; j < 3; ++j)
        ev[j] = *reinterpret_cast<const float4*>(emb + (size_t)myidx[j] * ND + hl * 4);

    // --- coalesced constant-label writes (one masked store each)
    if (half == 0 && hl == 0)
        out[NB + row] = 1.0f;                              // pos_label
    if (half == 0 && hl < NS)
        out[2 * NB + NB * NS + row * NS + hl] = 0.0f;      // neg_label row (20B coalesced)

    // --- reduce + sigmoid + scattered result stores
#pragma unroll
    for (int j = 0; j < 3; ++j) {
        const int s_abs = 2 * j + half;   // absolute sample id 0..5
        float sum = hv.x * ev[j].x + hv.y * ev[j].y + hv.z * ev[j].z + hv.w * ev[j].w;
        // 32-lane butterfly (xor offsets 1..16 stay within each half)
#pragma unroll
        for (int off = 16; off >= 1; off >>= 1)
            sum += __shfl_xor(sum, off, 64);
        if (hl == 0) {
            const float sig = 1.0f / (1.0f + __expf(-sum));
            if (s_abs == 0) {
                out[row] = sig;                              // pos_out
            } else {
                out[2 * NB + row * NS + (s_abs - 1)] = sig;  // neg_out
            }
        }
    }
}

extern "C" void kernel_launch(void* const* d_in, const int* in_sizes, int n_in,
                              void* d_out, int out_size, void* d_ws, size_t ws_size,
                              hipStream_t stream) {
    const float* h   = (const float*)d_in[0];
    const float* emb = (const float*)d_in[1];
    const int*   tgt = (const int*)d_in[2];
    const int*   neg = (const int*)d_in[3];
    float*       out = (float*)d_out;

    // one wave per row; 4 waves per 256-thread block
    const int blocks = NB / 4;  // 4096
    ws_negsamp_kernel<<<blocks, 256, 0, stream>>>(h, emb, tgt, neg, out);
}